// Round 2
// baseline (284.808 us; speedup 1.0000x reference)
//
#include <hip/hip_runtime.h>

typedef unsigned short ushort_t;
typedef unsigned int uint_t;
typedef __attribute__((ext_vector_type(8))) short short8;
typedef __attribute__((ext_vector_type(8))) _Float16 half8;
typedef __attribute__((ext_vector_type(4))) float float4v;

#define MFMA_BF16(a, b, c) __builtin_amdgcn_mfma_f32_16x16x32_bf16((a), (b), (c), 0, 0, 0)
#define MFMA_F16(a, b, c) __builtin_amdgcn_mfma_f32_16x16x32_f16((a), (b), (c), 0, 0, 0)

#define NQ 8192
#define DIM 256
#define DV 512

// round-to-nearest-even f32 -> bf16 (returned as raw bits)
__device__ __forceinline__ ushort_t f2bf(float x) {
  union { float f; uint_t u; } v; v.f = x;
  return (ushort_t)((v.u + 0x7fffu + ((v.u >> 16) & 1u)) >> 16);
}
// bf16 bits -> f32
__device__ __forceinline__ float bf2f(ushort_t b) {
  union { uint_t u; float f; } v; v.u = ((uint_t)b) << 16;
  return v.f;
}

__device__ __forceinline__ half8 cvt8h(const float* p) {
  float4v a = *(const float4v*)p;
  float4v b = *(const float4v*)(p + 4);
  half8 r;
  r[0] = (_Float16)a[0]; r[1] = (_Float16)a[1];
  r[2] = (_Float16)a[2]; r[3] = (_Float16)a[3];
  r[4] = (_Float16)b[0]; r[5] = (_Float16)b[1];
  r[6] = (_Float16)b[2]; r[7] = (_Float16)b[3];
  return r;
}

__device__ __forceinline__ half8 as_h8(short8 s) {
  union { short8 s; half8 h; } u; u.s = s; return u.h;
}

// async global->LDS, 16B per lane; lds dest must be wave-uniform (HW adds lane*16)
__device__ __forceinline__ void load_lds_16(const void* g, void* l) {
  __builtin_amdgcn_global_load_lds(
      (const __attribute__((address_space(1))) uint_t*)g,
      (__attribute__((address_space(3))) uint_t*)l, 16, 0, 0);
}

// ---------------- projection: Qh = f16(img @ Wq^T), Kh = f16(text @ Wk^T) ----------------
// grid (128, 4, 2), block 256. Tile: 64 rows x 64 cols, wave owns 16 rows x 64 cols.
__global__ __launch_bounds__(256, 2) void proj_kernel(
    const float* __restrict__ img, const float* __restrict__ text,
    const float* __restrict__ Wq, const float* __restrict__ Wk,
    _Float16* __restrict__ Qh, _Float16* __restrict__ Kh) {
  const int lane = threadIdx.x & 63;
  const int wv = threadIdx.x >> 6;
  const int l16 = lane & 15;
  const int quad = lane >> 4;
  const float* A = blockIdx.z ? text : img;
  const float* W = blockIdx.z ? Wk : Wq;
  _Float16* C = blockIdx.z ? Kh : Qh;
  const int row = blockIdx.x * 64 + wv * 16 + l16;
  const int colbase = blockIdx.y * 64;

  float4v acc[4];
#pragma unroll
  for (int c = 0; c < 4; ++c) acc[c] = (float4v){0.f, 0.f, 0.f, 0.f};

#pragma unroll
  for (int f = 0; f < 8; ++f) {
    const int k0 = f * 32 + quad * 8;
    half8 af = cvt8h(A + (size_t)row * DIM + k0);
#pragma unroll
    for (int c = 0; c < 4; ++c) {
      half8 bfr = cvt8h(W + (size_t)(colbase + c * 16 + l16) * DIM + k0);
      acc[c] = MFMA_F16(af, bfr, acc[c]);
    }
  }
  const int rbase = blockIdx.x * 64 + wv * 16 + quad * 4;
#pragma unroll
  for (int c = 0; c < 4; ++c)
#pragma unroll
    for (int r = 0; r < 4; ++r)
      C[(size_t)(rbase + r) * DIM + colbase + c * 16 + l16] = (_Float16)acc[c][r];
}

// ---------------- Vt = bf16([img | text]^T), shape [512][8192] ----------------
__global__ __launch_bounds__(256) void make_vt_kernel(
    const float* __restrict__ img, const float* __restrict__ text,
    ushort_t* __restrict__ Vt) {
  __shared__ float tile[64][65];
  const int n0 = blockIdx.x * 64;
  const int c0 = blockIdx.y * 64;
  const float* src = (c0 < 256) ? img : text;
  const int cc0 = (c0 < 256) ? c0 : (c0 - 256);
  const int tid = threadIdx.x;

#pragma unroll
  for (int i = 0; i < 4; ++i) {
    const int r = i * 16 + (tid >> 4);
    const int c = (tid & 15) * 4;
    *(float4v*)&tile[r][c] = *(const float4v*)(src + (size_t)(n0 + r) * DIM + cc0 + c);
  }
  __syncthreads();
  const int c = tid >> 2;
  const int seg = tid & 3;
  ushort_t tmp[16];
#pragma unroll
  for (int t = 0; t < 16; ++t) tmp[t] = f2bf(tile[seg * 16 + t][c]);
  ushort_t* dst = Vt + (size_t)(c0 + c) * NQ + n0 + seg * 16;
  *(short8*)dst = *(short8*)&tmp[0];
  *(short8*)(dst + 8) = *(short8*)&tmp[8];
}

// ---------------- fused attention (no-max streaming softmax, split-K) ----------------
__global__ __launch_bounds__(256, 2) void attn_kernel(
    const _Float16* __restrict__ Qh, const _Float16* __restrict__ Kh,
    const ushort_t* __restrict__ Vt, float* __restrict__ pacc,
    float* __restrict__ pdenom, int kps) {
  __shared__ __align__(16) ushort_t ldsK[32 * DIM];
  __shared__ __align__(16) ushort_t ldsV[DV * 32];
  __shared__ __align__(16) ushort_t ldsP[4 * 16 * 40];

  const int tid = threadIdx.x;
  const int lane = tid & 63;
  const int wv = tid >> 6;
  const int l16 = lane & 15;
  const int quad = lane >> 4;
  const int qtile = blockIdx.x;
  const int split = blockIdx.y;
  const int kbeg = split * kps;

  short8 qf[8];
  {
    const _Float16* qptr = Qh + (size_t)(qtile * 64 + wv * 16 + l16) * DIM;
#pragma unroll
    for (int f = 0; f < 8; ++f)
      qf[f] = *(const short8*)(qptr + f * 32 + quad * 8);
  }

  float4v acc[32];
#pragma unroll
  for (int t = 0; t < 32; ++t) acc[t] = (float4v){0.f, 0.f, 0.f, 0.f};
  float dacc[4] = {0.f, 0.f, 0.f, 0.f};

  ushort_t* pb = ldsP + wv * 640;

  const int ntiles = kps >> 5;
  for (int it = 0; it < ntiles; ++it) {
    const int k0 = kbeg + it * 32;
    __syncthreads();
#pragma unroll
    for (int i = 0; i < 4; ++i) {
      const int chunk = i * 256 + tid;
      const int n = chunk >> 5;
      const int cs = (chunk & 31) ^ (n & 7);
      load_lds_16(Kh + (size_t)(k0 + n) * DIM + cs * 8,
                  (char*)ldsK + (i * 256 + wv * 64) * 16);
    }
#pragma unroll
    for (int i = 0; i < 8; ++i) {
      const int chunk = i * 256 + tid;
      const int vrow = chunk >> 2;
      const int off = (chunk & 3) * 8;
      load_lds_16(Vt + (size_t)vrow * NQ + k0 + off,
                  (char*)ldsV + (i * 256 + wv * 64) * 16);
    }
    __syncthreads();

    // S = Q K^T (16 q-rows x 32 keys), f16 inputs, fp32 acc
    float4v s0 = (float4v){0.f, 0.f, 0.f, 0.f};
    float4v s1 = (float4v){0.f, 0.f, 0.f, 0.f};
    const int sw = l16 & 7;
#pragma unroll
    for (int f = 0; f < 8; ++f) {
      const int cs = ((f * 4 + quad) ^ sw) * 8;
      short8 kb0 = *(const short8*)(ldsK + l16 * DIM + cs);
      short8 kb1 = *(const short8*)(ldsK + (l16 + 16) * DIM + cs);
      s0 = MFMA_F16(as_h8(qf[f]), as_h8(kb0), s0);
      s1 = MFMA_F16(as_h8(qf[f]), as_h8(kb1), s1);
    }

    // P = exp(S); round to bf16 and sum the ROUNDED values for the denominator
    ushort_t pb0[4], pb1[4];
    float p0[4], p1[4];
#pragma unroll
    for (int r = 0; r < 4; ++r) {
      pb0[r] = f2bf(__expf(s0[r]));
      pb1[r] = f2bf(__expf(s1[r]));
      p0[r] = bf2f(pb0[r]);
      p1[r] = bf2f(pb1[r]);
    }
#pragma unroll
    for (int r = 0; r < 4; ++r) {
      float t = p0[r] + p1[r];
      t += __shfl_xor(t, 1);
      t += __shfl_xor(t, 2);
      t += __shfl_xor(t, 4);
      t += __shfl_xor(t, 8);
      dacc[r] += t;
    }
#pragma unroll
    for (int r = 0; r < 4; ++r) {
      pb[(quad * 4 + r) * 40 + l16] = pb0[r];
      pb[(quad * 4 + r) * 40 + l16 + 16] = pb1[r];
    }
    __threadfence_block();
    short8 pa = *(const short8*)(pb + l16 * 40 + quad * 8);

    // acc += P @ V  (32 vcol tiles of 16), bf16
#pragma unroll
    for (int c = 0; c < 32; ++c) {
      short8 vb = *(const short8*)(ldsV + (c * 16 + l16) * 32 + quad * 8);
      acc[c] = MFMA_BF16(pa, vb, acc[c]);
    }
  }

  float* pout = pacc + (size_t)split * ((size_t)NQ * DV);
  const int rowbase = qtile * 64 + wv * 16 + quad * 4;
#pragma unroll
  for (int c = 0; c < 32; ++c)
#pragma unroll
    for (int r = 0; r < 4; ++r)
      pout[(size_t)(rowbase + r) * DV + c * 16 + l16] = acc[c][r];
  if (l16 == 0) {
#pragma unroll
    for (int r = 0; r < 4; ++r)
      pdenom[split * NQ + rowbase + r] = dacc[r];
  }
}

// ---------------- combine partials, normalize, write [out_img | out_text] ----------------
__global__ __launch_bounds__(256) void combine_kernel(
    const float* __restrict__ pacc, const float* __restrict__ pdenom,
    float* __restrict__ out, int ks) {
  const int idx = blockIdx.x * 256 + threadIdx.x;
  const int n = idx >> 7;
  const int c4 = (idx & 127) << 2;
  float4v s = (float4v){0.f, 0.f, 0.f, 0.f};
  float d = 0.f;
  for (int sp = 0; sp < ks; ++sp) {
    s += *(const float4v*)(pacc + (size_t)sp * ((size_t)NQ * DV) + (size_t)n * DV + c4);
    d += pdenom[sp * NQ + n];
  }
  const float scale = 1.0f / (16.0f * d);
  s *= scale;
  float* dst = (c4 < 256) ? (out + (size_t)n * DIM + c4)
                          : (out + (size_t)NQ * DIM + (size_t)n * DIM + (c4 - 256));
  *(float4v*)dst = s;
}

extern "C" void kernel_launch(void* const* d_in, const int* in_sizes, int n_in,
                              void* d_out, int out_size, void* d_ws, size_t ws_size,
                              hipStream_t stream) {
  const float* img = (const float*)d_in[0];
  const float* text = (const float*)d_in[1];
  const float* Wq = (const float*)d_in[2];
  const float* Wk = (const float*)d_in[3];
  float* out = (float*)d_out;
  char* ws = (char*)d_ws;

  _Float16* Qh = (_Float16*)ws;                        // 4 MiB
  _Float16* Kh = (_Float16*)(ws + ((size_t)4 << 20));  // 4 MiB
  ushort_t* Vt = (ushort_t*)(ws + ((size_t)8 << 20));  // 8 MiB
  const size_t accsz = (size_t)NQ * DV * sizeof(float);  // 16 MiB per split
  const size_t base = (size_t)16 << 20;

  int ks = 4;
  if (ws_size < base + 4 * (accsz + NQ * sizeof(float))) ks = 2;
  if (ws_size < base + 2 * (accsz + NQ * sizeof(float))) ks = 1;
  float* pacc = (float*)(ws + base);
  float* pdenom = (float*)(ws + base + (size_t)ks * accsz);

  hipLaunchKernelGGL(proj_kernel, dim3(128, 4, 2), dim3(256), 0, stream,
                     img, text, Wq, Wk, Qh, Kh);
  hipLaunchKernelGGL(make_vt_kernel, dim3(128, 8), dim3(256), 0, stream,
                     img, text, Vt);
  hipLaunchKernelGGL(attn_kernel, dim3(128, ks), dim3(256), 0, stream,
                     Qh, Kh, Vt, pacc, pdenom, NQ / ks);
  hipLaunchKernelGGL(combine_kernel, dim3((NQ * DV / 4) / 256), dim3(256), 0, stream,
                     pacc, pdenom, out, ks);
}

// Round 3
// 275.398 us; speedup vs baseline: 1.0342x; 1.0342x over previous
//
#include <hip/hip_runtime.h>

typedef unsigned short ushort_t;
typedef unsigned int uint_t;
typedef __attribute__((ext_vector_type(8))) short short8;
typedef __attribute__((ext_vector_type(8))) _Float16 half8;
typedef __attribute__((ext_vector_type(4))) float float4v;

#define MFMA_BF16(a, b, c) __builtin_amdgcn_mfma_f32_16x16x32_bf16((a), (b), (c), 0, 0, 0)
#define MFMA_F16(a, b, c) __builtin_amdgcn_mfma_f32_16x16x32_f16((a), (b), (c), 0, 0, 0)

#define NQ 8192
#define DIM 256
#define DV 512

// round-to-nearest-even f32 -> bf16 (returned as raw bits)
__device__ __forceinline__ ushort_t f2bf(float x) {
  union { float f; uint_t u; } v; v.f = x;
  return (ushort_t)((v.u + 0x7fffu + ((v.u >> 16) & 1u)) >> 16);
}
__device__ __forceinline__ float bf2f(ushort_t b) {
  union { uint_t u; float f; } v; v.u = ((uint_t)b) << 16;
  return v.f;
}

__device__ __forceinline__ half8 cvt8h(const float* p) {
  float4v a = *(const float4v*)p;
  float4v b = *(const float4v*)(p + 4);
  half8 r;
  r[0] = (_Float16)a[0]; r[1] = (_Float16)a[1];
  r[2] = (_Float16)a[2]; r[3] = (_Float16)a[3];
  r[4] = (_Float16)b[0]; r[5] = (_Float16)b[1];
  r[6] = (_Float16)b[2]; r[7] = (_Float16)b[3];
  return r;
}

__device__ __forceinline__ half8 as_h8(short8 s) {
  union { short8 s; half8 h; } u; u.s = s; return u.h;
}

// async global->LDS, 16B per lane; lds dest is wave-uniform base (HW adds lane*16)
__device__ __forceinline__ void load_lds_16(const void* g, void* l) {
  __builtin_amdgcn_global_load_lds(
      (const __attribute__((address_space(1))) uint_t*)g,
      (__attribute__((address_space(3))) uint_t*)l, 16, 0, 0);
}

// ---------------- projection: Qh = f16(img @ Wq^T), Kh = f16(text @ Wk^T) ----------------
__global__ __launch_bounds__(256, 2) void proj_kernel(
    const float* __restrict__ img, const float* __restrict__ text,
    const float* __restrict__ Wq, const float* __restrict__ Wk,
    _Float16* __restrict__ Qh, _Float16* __restrict__ Kh) {
  const int lane = threadIdx.x & 63;
  const int wv = threadIdx.x >> 6;
  const int l16 = lane & 15;
  const int quad = lane >> 4;
  const float* A = blockIdx.z ? text : img;
  const float* W = blockIdx.z ? Wk : Wq;
  _Float16* C = blockIdx.z ? Kh : Qh;
  const int row = blockIdx.x * 64 + wv * 16 + l16;
  const int colbase = blockIdx.y * 64;

  float4v acc[4];
#pragma unroll
  for (int c = 0; c < 4; ++c) acc[c] = (float4v){0.f, 0.f, 0.f, 0.f};

#pragma unroll
  for (int f = 0; f < 8; ++f) {
    const int k0 = f * 32 + quad * 8;
    half8 af = cvt8h(A + (size_t)row * DIM + k0);
#pragma unroll
    for (int c = 0; c < 4; ++c) {
      half8 bfr = cvt8h(W + (size_t)(colbase + c * 16 + l16) * DIM + k0);
      acc[c] = MFMA_F16(af, bfr, acc[c]);
    }
  }
  const int rbase = blockIdx.x * 64 + wv * 16 + quad * 4;
#pragma unroll
  for (int c = 0; c < 4; ++c)
#pragma unroll
    for (int r = 0; r < 4; ++r)
      C[(size_t)(rbase + r) * DIM + colbase + c * 16 + l16] = (_Float16)acc[c][r];
}

// ---------------- Vt = bf16([img | text]^T), shape [512][8192] ----------------
__global__ __launch_bounds__(256) void make_vt_kernel(
    const float* __restrict__ img, const float* __restrict__ text,
    ushort_t* __restrict__ Vt) {
  __shared__ float tile[64][65];
  const int n0 = blockIdx.x * 64;
  const int c0 = blockIdx.y * 64;
  const float* src = (c0 < 256) ? img : text;
  const int cc0 = (c0 < 256) ? c0 : (c0 - 256);
  const int tid = threadIdx.x;

#pragma unroll
  for (int i = 0; i < 4; ++i) {
    const int r = i * 16 + (tid >> 4);
    const int c = (tid & 15) * 4;
    *(float4v*)&tile[r][c] = *(const float4v*)(src + (size_t)(n0 + r) * DIM + cc0 + c);
  }
  __syncthreads();
  const int c = tid >> 2;
  const int seg = tid & 3;
  ushort_t tmp[16];
#pragma unroll
  for (int t = 0; t < 16; ++t) tmp[t] = f2bf(tile[seg * 16 + t][c]);
  ushort_t* dst = Vt + (size_t)(c0 + c) * NQ + n0 + seg * 16;
  *(short8*)dst = *(short8*)&tmp[0];
  *(short8*)(dst + 8) = *(short8*)&tmp[8];
}

// ---------------- fused attention (no-max streaming softmax, split-K) ----------------
// Block = 64 q-rows, 4 waves. S phase: wave w owns q-rows w*16..w*16+15 (K-frags
// from swizzled ldsK). P block-shared in LDS (chunk-swizzled). PV phase: wave w
// owns vcols w*128..w*128+127 for ALL 64 q-rows -> V tile read once per block.
__global__ __launch_bounds__(256, 2) void attn_kernel(
    const _Float16* __restrict__ Qh, const _Float16* __restrict__ Kh,
    const ushort_t* __restrict__ Vt, float* __restrict__ pacc,
    float* __restrict__ pdenom, int kps) {
  __shared__ __align__(16) ushort_t ldsK[32 * DIM];   // 16 KB
  __shared__ __align__(16) ushort_t ldsV[DV * 32];    // 32 KB, [vcol][key], swizzled chunks
  __shared__ __align__(16) ushort_t ldsP[64 * 32];    // 4 KB,  [qrow][key], swizzled chunks

  const int tid = threadIdx.x;
  const int lane = tid & 63;
  const int wv = tid >> 6;
  const int l16 = lane & 15;
  const int quad = lane >> 4;
  const int qtile = blockIdx.x;
  const int split = blockIdx.y;
  const int kbeg = split * kps;
  const int sw2 = (l16 >> 1) & 3;  // chunk swizzle term for 64B-row buffers

  // Q fragments for this wave's 16 S-rows: A-layout m=l16, k=quad*8+j
  short8 qf[8];
  {
    const _Float16* qptr = Qh + (size_t)(qtile * 64 + wv * 16 + l16) * DIM;
#pragma unroll
    for (int f = 0; f < 8; ++f)
      qf[f] = *(const short8*)(qptr + f * 32 + quad * 8);
  }

  // acc[m][c]: q-row block m (16 rows), vcol tile c within wave's 128 cols
  float4v acc[4][8];
#pragma unroll
  for (int m = 0; m < 4; ++m)
#pragma unroll
    for (int c = 0; c < 8; ++c) acc[m][c] = (float4v){0.f, 0.f, 0.f, 0.f};
  float dacc[4] = {0.f, 0.f, 0.f, 0.f};

  const int ntiles = kps >> 5;
  for (int it = 0; it < ntiles; ++it) {
    const int k0 = kbeg + it * 32;
    __syncthreads();  // prior tile's K/V/P reads complete
    // stage K tile: 32 keys x 512B rows; position p in row n holds data chunk p^(n&7)
#pragma unroll
    for (int i = 0; i < 4; ++i) {
      const int chunk = i * 256 + tid;
      const int n = chunk >> 5;
      const int cs = (chunk & 31) ^ (n & 7);
      load_lds_16(Kh + (size_t)(k0 + n) * DIM + cs * 8,
                  (char*)ldsK + (i * 256 + wv * 64) * 16);
    }
    // stage Vt tile: 512 rows x 64B; position p in row r holds data chunk p^((r>>1)&3)
#pragma unroll
    for (int i = 0; i < 8; ++i) {
      const int chunk = i * 256 + tid;
      const int vrow = chunk >> 2;
      const int dc = (chunk & 3) ^ ((vrow >> 1) & 3);
      load_lds_16(Vt + (size_t)vrow * NQ + k0 + dc * 8,
                  (char*)ldsV + (i * 256 + wv * 64) * 16);
    }
    __syncthreads();  // staging visible

    // S = Q K^T (this wave's 16 q-rows x 32 keys), f16 inputs, fp32 acc
    float4v s0 = (float4v){0.f, 0.f, 0.f, 0.f};
    float4v s1 = (float4v){0.f, 0.f, 0.f, 0.f};
    const int swk = l16 & 7;
#pragma unroll
    for (int f = 0; f < 8; ++f) {
      const int cs = ((f * 4 + quad) ^ swk) * 8;
      short8 kb0 = *(const short8*)(ldsK + l16 * DIM + cs);
      short8 kb1 = *(const short8*)(ldsK + (l16 + 16) * DIM + cs);
      s0 = MFMA_F16(as_h8(qf[f]), as_h8(kb0), s0);
      s1 = MFMA_F16(as_h8(qf[f]), as_h8(kb1), s1);
    }

    // P = exp(S), bf16-rounded; denom sums the ROUNDED values (num/den consistent)
    ushort_t pb0[4], pb1[4];
#pragma unroll
    for (int r = 0; r < 4; ++r) {
      pb0[r] = f2bf(__expf(s0[r]));
      pb1[r] = f2bf(__expf(s1[r]));
    }
#pragma unroll
    for (int r = 0; r < 4; ++r) {
      float t = bf2f(pb0[r]) + bf2f(pb1[r]);
      t += __shfl_xor(t, 1);
      t += __shfl_xor(t, 2);
      t += __shfl_xor(t, 4);
      t += __shfl_xor(t, 8);
      dacc[r] += t;
    }
    // write P (block-shared, swizzled): row = wv*16+quad*4+r, key cols l16 / l16+16
    {
      const int swr = ((wv * 16 + quad * 4) >> 1) & 3;  // row>>1 & 3 (r adds 0..3)
#pragma unroll
      for (int r = 0; r < 4; ++r) {
        const int rb = wv * 16 + quad * 4 + r;
        const int swp = (rb >> 1) & 3;
        ldsP[rb * 32 + ((l16 >> 3) ^ swp) * 8 + (l16 & 7)] = pb0[r];
        ldsP[rb * 32 + ((2 + (l16 >> 3)) ^ swp) * 8 + (l16 & 7)] = pb1[r];
      }
      (void)swr;
    }
    __syncthreads();  // P visible to all waves

    // PV: wave w owns vcols [w*128, w*128+128); reads all 64 q-rows' P
    short8 pa[4];
#pragma unroll
    for (int m = 0; m < 4; ++m)
      pa[m] = *(const short8*)(ldsP + (m * 16 + l16) * 32 + (quad ^ sw2) * 8);
#pragma unroll
    for (int c = 0; c < 8; ++c) {
      const int vcol = (wv * 8 + c) * 16 + l16;
      short8 vb = *(const short8*)(ldsV + vcol * 32 + (quad ^ sw2) * 8);
#pragma unroll
      for (int m = 0; m < 4; ++m)
        acc[m][c] = MFMA_BF16(pa[m], vb, acc[m][c]);
    }
  }

  // epilogue: partial acc (wave w: rows m*16+quad*4+r, cols (wv*8+c)*16+l16) + denom
  float* pout = pacc + (size_t)split * ((size_t)NQ * DV);
#pragma unroll
  for (int m = 0; m < 4; ++m) {
    const int rowbase = qtile * 64 + m * 16 + quad * 4;
#pragma unroll
    for (int c = 0; c < 8; ++c) {
      const int col = (wv * 8 + c) * 16 + l16;
#pragma unroll
      for (int r = 0; r < 4; ++r)
        pout[(size_t)(rowbase + r) * DV + col] = acc[m][c][r];
    }
  }
  if (l16 == 0) {
    const int rowbase = qtile * 64 + wv * 16 + quad * 4;
#pragma unroll
    for (int r = 0; r < 4; ++r)
      pdenom[split * NQ + rowbase + r] = dacc[r];
  }
}

// ---------------- combine partials, normalize, write [out_img | out_text] ----------------
__global__ __launch_bounds__(256) void combine_kernel(
    const float* __restrict__ pacc, const float* __restrict__ pdenom,
    float* __restrict__ out, int ks) {
  const int idx = blockIdx.x * 256 + threadIdx.x;
  const int n = idx >> 7;
  const int c4 = (idx & 127) << 2;
  float4v s = (float4v){0.f, 0.f, 0.f, 0.f};
  float d = 0.f;
  for (int sp = 0; sp < ks; ++sp) {
    s += *(const float4v*)(pacc + (size_t)sp * ((size_t)NQ * DV) + (size_t)n * DV + c4);
    d += pdenom[sp * NQ + n];
  }
  const float scale = 1.0f / (16.0f * d);
  s *= scale;
  float* dst = (c4 < 256) ? (out + (size_t)n * DIM + c4)
                          : (out + (size_t)NQ * DIM + (size_t)n * DIM + (c4 - 256));
  *(float4v*)dst = s;
}

extern "C" void kernel_launch(void* const* d_in, const int* in_sizes, int n_in,
                              void* d_out, int out_size, void* d_ws, size_t ws_size,
                              hipStream_t stream) {
  const float* img = (const float*)d_in[0];
  const float* text = (const float*)d_in[1];
  const float* Wq = (const float*)d_in[2];
  const float* Wk = (const float*)d_in[3];
  float* out = (float*)d_out;
  char* ws = (char*)d_ws;

  _Float16* Qh = (_Float16*)ws;                        // 4 MiB
  _Float16* Kh = (_Float16*)(ws + ((size_t)4 << 20));  // 4 MiB
  ushort_t* Vt = (ushort_t*)(ws + ((size_t)8 << 20));  // 8 MiB
  const size_t accsz = (size_t)NQ * DV * sizeof(float);  // 16 MiB per split
  const size_t base = (size_t)16 << 20;

  int ks = 4;
  if (ws_size < base + 4 * (accsz + NQ * sizeof(float))) ks = 2;
  if (ws_size < base + 2 * (accsz + NQ * sizeof(float))) ks = 1;
  float* pacc = (float*)(ws + base);
  float* pdenom = (float*)(ws + base + (size_t)ks * accsz);

  hipLaunchKernelGGL(proj_kernel, dim3(128, 4, 2), dim3(256), 0, stream,
                     img, text, Wq, Wk, Qh, Kh);
  hipLaunchKernelGGL(make_vt_kernel, dim3(128, 8), dim3(256), 0, stream,
                     img, text, Vt);
  hipLaunchKernelGGL(attn_kernel, dim3(128, ks), dim3(256), 0, stream,
                     Qh, Kh, Vt, pacc, pdenom, NQ / ks);
  hipLaunchKernelGGL(combine_kernel, dim3((NQ * DV / 4) / 256), dim3(256), 0, stream,
                     pacc, pdenom, out, ks);
}

// Round 4
// 274.178 us; speedup vs baseline: 1.0388x; 1.0044x over previous
//
#include <hip/hip_runtime.h>

typedef unsigned short ushort_t;
typedef unsigned int uint_t;
typedef __attribute__((ext_vector_type(8))) short short8;
typedef __attribute__((ext_vector_type(8))) _Float16 half8;
typedef __attribute__((ext_vector_type(4))) float float4v;

#define MFMA_BF16(a, b, c) __builtin_amdgcn_mfma_f32_16x16x32_bf16((a), (b), (c), 0, 0, 0)
#define MFMA_F16(a, b, c) __builtin_amdgcn_mfma_f32_16x16x32_f16((a), (b), (c), 0, 0, 0)

#define NQ 8192
#define DIM 256
#define DV 512

// round-to-nearest-even f32 -> bf16 (returned as raw bits)
__device__ __forceinline__ ushort_t f2bf(float x) {
  union { float f; uint_t u; } v; v.f = x;
  return (ushort_t)((v.u + 0x7fffu + ((v.u >> 16) & 1u)) >> 16);
}
__device__ __forceinline__ float bf2f(ushort_t b) {
  union { uint_t u; float f; } v; v.u = ((uint_t)b) << 16;
  return v.f;
}

__device__ __forceinline__ half8 cvt8h(const float* p) {
  float4v a = *(const float4v*)p;
  float4v b = *(const float4v*)(p + 4);
  half8 r;
  r[0] = (_Float16)a[0]; r[1] = (_Float16)a[1];
  r[2] = (_Float16)a[2]; r[3] = (_Float16)a[3];
  r[4] = (_Float16)b[0]; r[5] = (_Float16)b[1];
  r[6] = (_Float16)b[2]; r[7] = (_Float16)b[3];
  return r;
}

__device__ __forceinline__ half8 as_h8(short8 s) {
  union { short8 s; half8 h; } u; u.s = s; return u.h;
}

// async global->LDS, 16B per lane; lds dest is wave-uniform base (HW adds lane*16)
__device__ __forceinline__ void load_lds_16(const void* g, void* l) {
  __builtin_amdgcn_global_load_lds(
      (const __attribute__((address_space(1))) uint_t*)g,
      (__attribute__((address_space(3))) uint_t*)l, 16, 0, 0);
}

// ---------------- projection: Qh = f16(img @ Wq^T), Kh = f16(text @ Wk^T) ----------------
__global__ __launch_bounds__(256, 2) void proj_kernel(
    const float* __restrict__ img, const float* __restrict__ text,
    const float* __restrict__ Wq, const float* __restrict__ Wk,
    _Float16* __restrict__ Qh, _Float16* __restrict__ Kh) {
  const int lane = threadIdx.x & 63;
  const int wv = threadIdx.x >> 6;
  const int l16 = lane & 15;
  const int quad = lane >> 4;
  const float* A = blockIdx.z ? text : img;
  const float* W = blockIdx.z ? Wk : Wq;
  _Float16* C = blockIdx.z ? Kh : Qh;
  const int row = blockIdx.x * 64 + wv * 16 + l16;
  const int colbase = blockIdx.y * 64;

  float4v acc[4];
#pragma unroll
  for (int c = 0; c < 4; ++c) acc[c] = (float4v){0.f, 0.f, 0.f, 0.f};

#pragma unroll
  for (int f = 0; f < 8; ++f) {
    const int k0 = f * 32 + quad * 8;
    half8 af = cvt8h(A + (size_t)row * DIM + k0);
#pragma unroll
    for (int c = 0; c < 4; ++c) {
      half8 bfr = cvt8h(W + (size_t)(colbase + c * 16 + l16) * DIM + k0);
      acc[c] = MFMA_F16(af, bfr, acc[c]);
    }
  }
  const int rbase = blockIdx.x * 64 + wv * 16 + quad * 4;
#pragma unroll
  for (int c = 0; c < 4; ++c)
#pragma unroll
    for (int r = 0; r < 4; ++r)
      C[(size_t)(rbase + r) * DIM + colbase + c * 16 + l16] = (_Float16)acc[c][r];
}

// ---------------- Vt = bf16([img | text]^T), shape [512][8192] ----------------
__global__ __launch_bounds__(256) void make_vt_kernel(
    const float* __restrict__ img, const float* __restrict__ text,
    ushort_t* __restrict__ Vt) {
  __shared__ float tile[64][65];
  const int n0 = blockIdx.x * 64;
  const int c0 = blockIdx.y * 64;
  const float* src = (c0 < 256) ? img : text;
  const int cc0 = (c0 < 256) ? c0 : (c0 - 256);
  const int tid = threadIdx.x;

#pragma unroll
  for (int i = 0; i < 4; ++i) {
    const int r = i * 16 + (tid >> 4);
    const int c = (tid & 15) * 4;
    *(float4v*)&tile[r][c] = *(const float4v*)(src + (size_t)(n0 + r) * DIM + cc0 + c);
  }
  __syncthreads();
  const int c = tid >> 2;
  const int seg = tid & 3;
  ushort_t tmp[16];
#pragma unroll
  for (int t = 0; t < 16; ++t) tmp[t] = f2bf(tile[seg * 16 + t][c]);
  ushort_t* dst = Vt + (size_t)(c0 + c) * NQ + n0 + seg * 16;
  *(short8*)dst = *(short8*)&tmp[0];
  *(short8*)(dst + 8) = *(short8*)&tmp[8];
}

// ---------------- fused attention (no-max streaming softmax, split-K) ----------------
// 1-D grid. When swz!=0 (ks==4): split = (id&7)>>1, qtile = ((id>>3)<<1)|(id&1),
// so every XCD (dispatch round-robins id%8) hosts exactly ONE split ->
// per-XCD staging working set = K-split (1MB) + V-split (2MB) = 3MB < 4MB L2.
__global__ __launch_bounds__(256, 2) void attn_kernel(
    const _Float16* __restrict__ Qh, const _Float16* __restrict__ Kh,
    const ushort_t* __restrict__ Vt, float* __restrict__ pacc,
    float* __restrict__ pdenom, int kps, int swz) {
  __shared__ __align__(16) ushort_t ldsK[32 * DIM];   // 16 KB
  __shared__ __align__(16) ushort_t ldsV[DV * 32];    // 32 KB, [vcol][key], swizzled chunks
  __shared__ __align__(16) ushort_t ldsP[64 * 32];    // 4 KB,  [qrow][key], swizzled chunks

  const int tid = threadIdx.x;
  const int lane = tid & 63;
  const int wv = tid >> 6;
  const int l16 = lane & 15;
  const int quad = lane >> 4;
  const int id = blockIdx.x;
  int qtile, split;
  if (swz) {
    split = (id & 7) >> 1;
    qtile = ((id >> 3) << 1) | (id & 1);
  } else {
    split = id >> 7;
    qtile = id & 127;
  }
  const int kbeg = split * kps;
  const int sw2 = (l16 >> 1) & 3;  // chunk swizzle term for 64B-row buffers

  // Q fragments for this wave's 16 S-rows: A-layout m=l16, k=quad*8+j
  short8 qf[8];
  {
    const _Float16* qptr = Qh + (size_t)(qtile * 64 + wv * 16 + l16) * DIM;
#pragma unroll
    for (int f = 0; f < 8; ++f)
      qf[f] = *(const short8*)(qptr + f * 32 + quad * 8);
  }

  // acc[m][c]: q-row block m (16 rows), vcol tile c within wave's 128 cols
  float4v acc[4][8];
#pragma unroll
  for (int m = 0; m < 4; ++m)
#pragma unroll
    for (int c = 0; c < 8; ++c) acc[m][c] = (float4v){0.f, 0.f, 0.f, 0.f};
  float dacc[4] = {0.f, 0.f, 0.f, 0.f};

  const int ntiles = kps >> 5;
  for (int it = 0; it < ntiles; ++it) {
    const int k0 = kbeg + it * 32;
    __syncthreads();  // prior tile's K/V/P reads complete
    // stage K tile: 32 keys x 512B rows; position p in row n holds data chunk p^(n&7)
#pragma unroll
    for (int i = 0; i < 4; ++i) {
      const int chunk = i * 256 + tid;
      const int n = chunk >> 5;
      const int cs = (chunk & 31) ^ (n & 7);
      load_lds_16(Kh + (size_t)(k0 + n) * DIM + cs * 8,
                  (char*)ldsK + (i * 256 + wv * 64) * 16);
    }
    // stage Vt tile: 512 rows x 64B; position p in row r holds data chunk p^((r>>1)&3)
#pragma unroll
    for (int i = 0; i < 8; ++i) {
      const int chunk = i * 256 + tid;
      const int vrow = chunk >> 2;
      const int dc = (chunk & 3) ^ ((vrow >> 1) & 3);
      load_lds_16(Vt + (size_t)vrow * NQ + k0 + dc * 8,
                  (char*)ldsV + (i * 256 + wv * 64) * 16);
    }
    __syncthreads();  // staging visible

    // S = Q K^T (this wave's 16 q-rows x 32 keys), f16 inputs, fp32 acc
    float4v s0 = (float4v){0.f, 0.f, 0.f, 0.f};
    float4v s1 = (float4v){0.f, 0.f, 0.f, 0.f};
    const int swk = l16 & 7;
#pragma unroll
    for (int f = 0; f < 8; ++f) {
      const int cs = ((f * 4 + quad) ^ swk) * 8;
      short8 kb0 = *(const short8*)(ldsK + l16 * DIM + cs);
      short8 kb1 = *(const short8*)(ldsK + (l16 + 16) * DIM + cs);
      s0 = MFMA_F16(as_h8(qf[f]), as_h8(kb0), s0);
      s1 = MFMA_F16(as_h8(qf[f]), as_h8(kb1), s1);
    }

    // P = exp(S), bf16-rounded; denom sums the ROUNDED values (num/den consistent)
    ushort_t pb0[4], pb1[4];
#pragma unroll
    for (int r = 0; r < 4; ++r) {
      pb0[r] = f2bf(__expf(s0[r]));
      pb1[r] = f2bf(__expf(s1[r]));
    }
#pragma unroll
    for (int r = 0; r < 4; ++r) {
      float t = bf2f(pb0[r]) + bf2f(pb1[r]);
      t += __shfl_xor(t, 1);
      t += __shfl_xor(t, 2);
      t += __shfl_xor(t, 4);
      t += __shfl_xor(t, 8);
      dacc[r] += t;
    }
    // write P (block-shared, swizzled): row = wv*16+quad*4+r, key cols l16 / l16+16
#pragma unroll
    for (int r = 0; r < 4; ++r) {
      const int rb = wv * 16 + quad * 4 + r;
      const int swp = (rb >> 1) & 3;
      ldsP[rb * 32 + ((l16 >> 3) ^ swp) * 8 + (l16 & 7)] = pb0[r];
      ldsP[rb * 32 + ((2 + (l16 >> 3)) ^ swp) * 8 + (l16 & 7)] = pb1[r];
    }
    __syncthreads();  // P visible to all waves

    // PV: wave w owns vcols [w*128, w*128+128); reads all 64 q-rows' P
    short8 pa[4];
#pragma unroll
    for (int m = 0; m < 4; ++m)
      pa[m] = *(const short8*)(ldsP + (m * 16 + l16) * 32 + (quad ^ sw2) * 8);
#pragma unroll
    for (int c = 0; c < 8; ++c) {
      const int vcol = (wv * 8 + c) * 16 + l16;
      short8 vb = *(const short8*)(ldsV + vcol * 32 + (quad ^ sw2) * 8);
#pragma unroll
      for (int m = 0; m < 4; ++m)
        acc[m][c] = MFMA_BF16(pa[m], vb, acc[m][c]);
    }
  }

  // epilogue: partial acc (wave w: rows m*16+quad*4+r, cols (wv*8+c)*16+l16) + denom
  float* pout = pacc + (size_t)split * ((size_t)NQ * DV);
#pragma unroll
  for (int m = 0; m < 4; ++m) {
    const int rowbase = qtile * 64 + m * 16 + quad * 4;
#pragma unroll
    for (int c = 0; c < 8; ++c) {
      const int col = (wv * 8 + c) * 16 + l16;
#pragma unroll
      for (int r = 0; r < 4; ++r)
        pout[(size_t)(rowbase + r) * DV + col] = acc[m][c][r];
    }
  }
  if (l16 == 0) {
    const int rowbase = qtile * 64 + wv * 16 + quad * 4;
#pragma unroll
    for (int r = 0; r < 4; ++r)
      pdenom[split * NQ + rowbase + r] = dacc[r];
  }
}

// ---------------- combine partials, normalize, write [out_img | out_text] ----------------
__global__ __launch_bounds__(256) void combine_kernel(
    const float* __restrict__ pacc, const float* __restrict__ pdenom,
    float* __restrict__ out, int ks) {
  const int idx = blockIdx.x * 256 + threadIdx.x;
  const int n = idx >> 7;
  const int c4 = (idx & 127) << 2;
  float4v s = (float4v){0.f, 0.f, 0.f, 0.f};
  float d = 0.f;
  for (int sp = 0; sp < ks; ++sp) {
    s += *(const float4v*)(pacc + (size_t)sp * ((size_t)NQ * DV) + (size_t)n * DV + c4);
    d += pdenom[sp * NQ + n];
  }
  const float scale = 1.0f / (16.0f * d);
  s *= scale;
  float* dst = (c4 < 256) ? (out + (size_t)n * DIM + c4)
                          : (out + (size_t)NQ * DIM + (size_t)n * DIM + (c4 - 256));
  *(float4v*)dst = s;
}

extern "C" void kernel_launch(void* const* d_in, const int* in_sizes, int n_in,
                              void* d_out, int out_size, void* d_ws, size_t ws_size,
                              hipStream_t stream) {
  const float* img = (const float*)d_in[0];
  const float* text = (const float*)d_in[1];
  const float* Wq = (const float*)d_in[2];
  const float* Wk = (const float*)d_in[3];
  float* out = (float*)d_out;
  char* ws = (char*)d_ws;

  _Float16* Qh = (_Float16*)ws;                        // 4 MiB
  _Float16* Kh = (_Float16*)(ws + ((size_t)4 << 20));  // 4 MiB
  ushort_t* Vt = (ushort_t*)(ws + ((size_t)8 << 20));  // 8 MiB
  const size_t accsz = (size_t)NQ * DV * sizeof(float);  // 16 MiB per split
  const size_t base = (size_t)16 << 20;

  int ks = 4;
  if (ws_size < base + 4 * (accsz + NQ * sizeof(float))) ks = 2;
  if (ws_size < base + 2 * (accsz + NQ * sizeof(float))) ks = 1;
  float* pacc = (float*)(ws + base);
  float* pdenom = (float*)(ws + base + (size_t)ks * accsz);
  const int swz = (ks == 4) ? 1 : 0;

  hipLaunchKernelGGL(proj_kernel, dim3(128, 4, 2), dim3(256), 0, stream,
                     img, text, Wq, Wk, Qh, Kh);
  hipLaunchKernelGGL(make_vt_kernel, dim3(128, 8), dim3(256), 0, stream,
                     img, text, Vt);
  hipLaunchKernelGGL(attn_kernel, dim3(128 * ks), dim3(256), 0, stream,
                     Qh, Kh, Vt, pacc, pdenom, NQ / ks, swz);
  hipLaunchKernelGGL(combine_kernel, dim3((NQ * DV / 4) / 256), dim3(256), 0, stream,
                     pacc, pdenom, out, ks);
}